// Round 1
// baseline (34.040 us; speedup 1.0000x reference)
//
#include <hip/hip_runtime.h>

// Problem constants (match reference): P=40000, DEG=16, CI=CO=16.
// Sizes derived from in_sizes at runtime where cheap.

// ---------------------------------------------------------------------------
// Phase 1: g[p][d][o] = sum_i W[d][o][i] * features[p][i]
// One thread per (p, o); block = 256 threads = 16 points.
// ---------------------------------------------------------------------------
__global__ __launch_bounds__(256) void k_transform(const float* __restrict__ feat,
                                                   const float* __restrict__ W,
                                                   float* __restrict__ g,
                                                   int P) {
    __shared__ float Wt[3][16][16];  // Wt[d][i][o] = W[d][o][i] (transposed for bank-friendly reads)
    const int tid = threadIdx.x;
    for (int t = tid; t < 768; t += 256) {
        const int d = t >> 8;
        const int o = (t >> 4) & 15;
        const int i = t & 15;
        Wt[d][i][o] = W[t];          // W flat layout [3][16][16] row-major
    }
    __syncthreads();

    const int idx = blockIdx.x * 256 + tid;   // (p, o)
    const int p = idx >> 4;
    const int o = idx & 15;
    if (p >= P) return;

    const float4* f4 = reinterpret_cast<const float4*>(feat + (size_t)p * 16);
    const float4 a = f4[0], b = f4[1], c = f4[2], d4 = f4[3];
    float f[16];
    f[0]=a.x;  f[1]=a.y;  f[2]=a.z;  f[3]=a.w;
    f[4]=b.x;  f[5]=b.y;  f[6]=b.z;  f[7]=b.w;
    f[8]=c.x;  f[9]=c.y;  f[10]=c.z; f[11]=c.w;
    f[12]=d4.x; f[13]=d4.y; f[14]=d4.z; f[15]=d4.w;

    float s0 = 0.f, s1 = 0.f, s2 = 0.f;
#pragma unroll
    for (int i = 0; i < 16; ++i) {
        const float fi = f[i];
        s0 += Wt[0][i][o] * fi;
        s1 += Wt[1][i][o] * fi;
        s2 += Wt[2][i][o] * fi;
    }
    float* gp = g + (size_t)p * 48;   // layout [p][d][16]
    gp[o]      = s0;
    gp[16 + o] = s1;
    gp[32 + o] = s2;
}

// ---------------------------------------------------------------------------
// Phase 2: out[p][o] = sum_n sum_d radii[p*16+n][d] * g[nbr(p,n)][d][o]
// One thread per (p, o); block = 256 threads = 16 points.
// bs_slice rows + radii staged in LDS (broadcast across the 16 o-lanes).
// ---------------------------------------------------------------------------
__global__ __launch_bounds__(256) void k_gather(const float* __restrict__ g,
                                                const float* __restrict__ radii,
                                                const int* __restrict__ bs,
                                                float* __restrict__ out,
                                                int P) {
    __shared__ int   s_nbr[16][16];
    __shared__ float s_r[16][48];     // [local point][n*3 + d]
    const int tid = threadIdx.x;
    const int pbase = blockIdx.x * 16;

    {
        const int lp = tid >> 4, n = tid & 15;
        const int p = pbase + lp;
        s_nbr[lp][n] = (p < P) ? bs[(size_t)p * 17 + 1 + n] : 0;
    }
    {
        float* srf = &s_r[0][0];
        const size_t lim = (size_t)P * 48;
        for (int t = tid; t < 768; t += 256) {
            const size_t gi = (size_t)pbase * 48 + t;
            srf[t] = (gi < lim) ? radii[gi] : 0.f;
        }
    }
    __syncthreads();

    const int lp = tid >> 4, o = tid & 15;
    const int p = pbase + lp;
    if (p >= P) return;

    float acc = 0.f;
#pragma unroll
    for (int n = 0; n < 16; ++n) {
        const int src = s_nbr[lp][n];
        const float* gs = g + (size_t)src * 48;
        const float r0 = s_r[lp][n * 3 + 0];
        const float r1 = s_r[lp][n * 3 + 1];
        const float r2 = s_r[lp][n * 3 + 2];
        acc += r0 * gs[o] + r1 * gs[16 + o] + r2 * gs[32 + o];
    }
    out[(size_t)p * 16 + o] = acc;
}

// ---------------------------------------------------------------------------
// Fallback (ws too small): fully fused, per-edge recompute of the transform.
// ---------------------------------------------------------------------------
__global__ __launch_bounds__(256) void k_fused(const float* __restrict__ feat,
                                               const float* __restrict__ radii,
                                               const float* __restrict__ W,
                                               const int* __restrict__ bs,
                                               float* __restrict__ out,
                                               int P) {
    __shared__ float Wt[3][16][16];
    __shared__ int   s_nbr[16][16];
    __shared__ float s_r[16][48];
    const int tid = threadIdx.x;
    const int pbase = blockIdx.x * 16;

    for (int t = tid; t < 768; t += 256) {
        const int d = t >> 8;
        const int o = (t >> 4) & 15;
        const int i = t & 15;
        Wt[d][i][o] = W[t];
    }
    {
        const int lp = tid >> 4, n = tid & 15;
        const int p = pbase + lp;
        s_nbr[lp][n] = (p < P) ? bs[(size_t)p * 17 + 1 + n] : 0;
    }
    {
        float* srf = &s_r[0][0];
        const size_t lim = (size_t)P * 48;
        for (int t = tid; t < 768; t += 256) {
            const size_t gi = (size_t)pbase * 48 + t;
            srf[t] = (gi < lim) ? radii[gi] : 0.f;
        }
    }
    __syncthreads();

    const int lp = tid >> 4, o = tid & 15;
    const int p = pbase + lp;
    if (p >= P) return;

    float acc = 0.f;
    for (int n = 0; n < 16; ++n) {
        const int src = s_nbr[lp][n];
        const float4* f4 = reinterpret_cast<const float4*>(feat + (size_t)src * 16);
        const float4 a = f4[0], b = f4[1], c = f4[2], d4 = f4[3];
        float f[16];
        f[0]=a.x;  f[1]=a.y;  f[2]=a.z;  f[3]=a.w;
        f[4]=b.x;  f[5]=b.y;  f[6]=b.z;  f[7]=b.w;
        f[8]=c.x;  f[9]=c.y;  f[10]=c.z; f[11]=c.w;
        f[12]=d4.x; f[13]=d4.y; f[14]=d4.z; f[15]=d4.w;
        float s0 = 0.f, s1 = 0.f, s2 = 0.f;
#pragma unroll
        for (int i = 0; i < 16; ++i) {
            const float fi = f[i];
            s0 += Wt[0][i][o] * fi;
            s1 += Wt[1][i][o] * fi;
            s2 += Wt[2][i][o] * fi;
        }
        acc += s_r[lp][n * 3 + 0] * s0
             + s_r[lp][n * 3 + 1] * s1
             + s_r[lp][n * 3 + 2] * s2;
    }
    out[(size_t)p * 16 + o] = acc;
}

extern "C" void kernel_launch(void* const* d_in, const int* in_sizes, int n_in,
                              void* d_out, int out_size, void* d_ws, size_t ws_size,
                              hipStream_t stream) {
    const float* feat  = (const float*)d_in[0];   // [P,16] f32
    const float* radii = (const float*)d_in[1];   // [E,3]  f32
    const float* W     = (const float*)d_in[2];   // [3,16,16] f32
    const int*   bs    = (const int*)d_in[3];     // [P,17] i32
    float* out = (float*)d_out;                   // [P,16] f32

    const int P = in_sizes[0] / 16;
    const size_t need = (size_t)P * 48 * sizeof(float);

    if (ws_size >= need) {
        float* g = (float*)d_ws;                  // [P][3][16]
        const int grid1 = (P * 16 + 255) / 256;
        const int grid2 = (P + 15) / 16;
        k_transform<<<grid1, 256, 0, stream>>>(feat, W, g, P);
        k_gather<<<grid2, 256, 0, stream>>>(g, radii, bs, out, P);
    } else {
        const int grid = (P + 15) / 16;
        k_fused<<<grid, 256, 0, stream>>>(feat, radii, W, bs, out, P);
    }
}

// Round 2
// 24.572 us; speedup vs baseline: 1.3853x; 1.3853x over previous
//
#include <hip/hip_runtime.h>
#include <hip/hip_fp16.h>

// P=40000, DEG=16, CI=CO=16.
// Two-phase: (1) per-point feature transform g[p][o] = {sum_i W[d][o][i]*f[p][i]}_d
// packed as 4x f16 (h0,h1,h2,0) = 8 B per (p,o); (2) per-edge gather
// msg[p][o] = sum_n sum_d r[p,n,d] * g[nbr][o].d  with ONE dwordx2 load per edge-lane.

// ---------------------------------------------------------------------------
// Phase 1: one thread per (p, o); block = 256 threads = 16 points.
// ---------------------------------------------------------------------------
__global__ __launch_bounds__(256) void k_transform(const float* __restrict__ feat,
                                                   const float* __restrict__ W,
                                                   uint2* __restrict__ g,   // [P*16] packed {h0,h1,h2,pad}
                                                   int P) {
    __shared__ float Wt[3][16][16];  // Wt[d][i][o] = W[d][o][i]
    const int tid = threadIdx.x;
    for (int t = tid; t < 768; t += 256) {
        const int d = t >> 8;
        const int o = (t >> 4) & 15;
        const int i = t & 15;
        Wt[d][i][o] = W[t];
    }
    __syncthreads();

    const int idx = blockIdx.x * 256 + tid;   // (p, o)
    const int p = idx >> 4;
    const int o = idx & 15;
    if (p >= P) return;

    const float4* f4 = reinterpret_cast<const float4*>(feat + (size_t)p * 16);
    const float4 a = f4[0], b = f4[1], c = f4[2], d4 = f4[3];
    float f[16];
    f[0]=a.x;  f[1]=a.y;  f[2]=a.z;  f[3]=a.w;
    f[4]=b.x;  f[5]=b.y;  f[6]=b.z;  f[7]=b.w;
    f[8]=c.x;  f[9]=c.y;  f[10]=c.z; f[11]=c.w;
    f[12]=d4.x; f[13]=d4.y; f[14]=d4.z; f[15]=d4.w;

    float s0 = 0.f, s1 = 0.f, s2 = 0.f;
#pragma unroll
    for (int i = 0; i < 16; ++i) {
        const float fi = f[i];
        s0 += Wt[0][i][o] * fi;
        s1 += Wt[1][i][o] * fi;
        s2 += Wt[2][i][o] * fi;
    }
    // pack {f16(s0), f16(s1), f16(s2), 0} into 8 B
    __half2 lo = __floats2half2_rn(s0, s1);
    __half2 hi = __floats2half2_rn(s2, 0.f);
    uint2 v;
    v.x = *reinterpret_cast<unsigned int*>(&lo);
    v.y = *reinterpret_cast<unsigned int*>(&hi);
    g[(size_t)p * 16 + o] = v;
}

// ---------------------------------------------------------------------------
// Phase 2: one thread per (p, o); block = 256 threads = 16 points.
// One dwordx2 load per (edge, o-lane): 128 B per edge across the 16-lane group.
// ---------------------------------------------------------------------------
__global__ __launch_bounds__(256) void k_gather(const uint2* __restrict__ g,
                                                const float* __restrict__ radii,
                                                const int* __restrict__ bs,
                                                float* __restrict__ out,
                                                int P) {
    __shared__ int   s_nbr[16][16];
    __shared__ float s_r[16][48];     // [local point][n*3 + d]
    const int tid = threadIdx.x;
    const int pbase = blockIdx.x * 16;

    {
        const int lp = tid >> 4, n = tid & 15;
        const int p = pbase + lp;
        s_nbr[lp][n] = (p < P) ? bs[(size_t)p * 17 + 1 + n] : 0;
    }
    {
        float* srf = &s_r[0][0];
        const size_t lim = (size_t)P * 48;
        for (int t = tid; t < 768; t += 256) {
            const size_t gi = (size_t)pbase * 48 + t;
            srf[t] = (gi < lim) ? radii[gi] : 0.f;
        }
    }
    __syncthreads();

    const int lp = tid >> 4, o = tid & 15;
    const int p = pbase + lp;
    if (p >= P) return;

    float acc0 = 0.f, acc1 = 0.f, acc2 = 0.f;
#pragma unroll
    for (int n = 0; n < 16; ++n) {
        const int src = s_nbr[lp][n];
        const uint2 v = g[(size_t)src * 16 + o];
        const __half2 lo = *reinterpret_cast<const __half2*>(&v.x);
        const __half2 hi = *reinterpret_cast<const __half2*>(&v.y);
        const float g0 = __low2float(lo);
        const float g1 = __high2float(lo);
        const float g2 = __low2float(hi);
        acc0 += s_r[lp][n * 3 + 0] * g0;
        acc1 += s_r[lp][n * 3 + 1] * g1;
        acc2 += s_r[lp][n * 3 + 2] * g2;
    }
    out[(size_t)p * 16 + o] = acc0 + acc1 + acc2;
}

// ---------------------------------------------------------------------------
// Fallback (ws too small): fully fused, per-edge recompute of the transform.
// ---------------------------------------------------------------------------
__global__ __launch_bounds__(256) void k_fused(const float* __restrict__ feat,
                                               const float* __restrict__ radii,
                                               const float* __restrict__ W,
                                               const int* __restrict__ bs,
                                               float* __restrict__ out,
                                               int P) {
    __shared__ float Wt[3][16][16];
    __shared__ int   s_nbr[16][16];
    __shared__ float s_r[16][48];
    const int tid = threadIdx.x;
    const int pbase = blockIdx.x * 16;

    for (int t = tid; t < 768; t += 256) {
        const int d = t >> 8;
        const int o = (t >> 4) & 15;
        const int i = t & 15;
        Wt[d][i][o] = W[t];
    }
    {
        const int lp = tid >> 4, n = tid & 15;
        const int p = pbase + lp;
        s_nbr[lp][n] = (p < P) ? bs[(size_t)p * 17 + 1 + n] : 0;
    }
    {
        float* srf = &s_r[0][0];
        const size_t lim = (size_t)P * 48;
        for (int t = tid; t < 768; t += 256) {
            const size_t gi = (size_t)pbase * 48 + t;
            srf[t] = (gi < lim) ? radii[gi] : 0.f;
        }
    }
    __syncthreads();

    const int lp = tid >> 4, o = tid & 15;
    const int p = pbase + lp;
    if (p >= P) return;

    float acc = 0.f;
    for (int n = 0; n < 16; ++n) {
        const int src = s_nbr[lp][n];
        const float4* f4 = reinterpret_cast<const float4*>(feat + (size_t)src * 16);
        const float4 a = f4[0], b = f4[1], c = f4[2], d4 = f4[3];
        float f[16];
        f[0]=a.x;  f[1]=a.y;  f[2]=a.z;  f[3]=a.w;
        f[4]=b.x;  f[5]=b.y;  f[6]=b.z;  f[7]=b.w;
        f[8]=c.x;  f[9]=c.y;  f[10]=c.z; f[11]=c.w;
        f[12]=d4.x; f[13]=d4.y; f[14]=d4.z; f[15]=d4.w;
        float s0 = 0.f, s1 = 0.f, s2 = 0.f;
#pragma unroll
        for (int i = 0; i < 16; ++i) {
            const float fi = f[i];
            s0 += Wt[0][i][o] * fi;
            s1 += Wt[1][i][o] * fi;
            s2 += Wt[2][i][o] * fi;
        }
        acc += s_r[lp][n * 3 + 0] * s0
             + s_r[lp][n * 3 + 1] * s1
             + s_r[lp][n * 3 + 2] * s2;
    }
    out[(size_t)p * 16 + o] = acc;
}

extern "C" void kernel_launch(void* const* d_in, const int* in_sizes, int n_in,
                              void* d_out, int out_size, void* d_ws, size_t ws_size,
                              hipStream_t stream) {
    const float* feat  = (const float*)d_in[0];   // [P,16] f32
    const float* radii = (const float*)d_in[1];   // [E,3]  f32
    const float* W     = (const float*)d_in[2];   // [3,16,16] f32
    const int*   bs    = (const int*)d_in[3];     // [P,17] i32
    float* out = (float*)d_out;                   // [P,16] f32

    const int P = in_sizes[0] / 16;
    const size_t need = (size_t)P * 16 * sizeof(uint2);   // packed g: 8 B per (p,o)

    if (ws_size >= need) {
        uint2* g = (uint2*)d_ws;                  // [P*16] packed {h0,h1,h2,pad}
        const int grid1 = (P * 16 + 255) / 256;
        const int grid2 = (P + 15) / 16;
        k_transform<<<grid1, 256, 0, stream>>>(feat, W, g, P);
        k_gather<<<grid2, 256, 0, stream>>>(g, radii, bs, out, P);
    } else {
        const int grid = (P + 15) / 16;
        k_fused<<<grid, 256, 0, stream>>>(feat, radii, W, bs, out, P);
    }
}